// Round 11
// baseline (1533.528 us; speedup 1.0000x reference)
//
#include <hip/hip_runtime.h>

typedef _Float16 fp16;
typedef _Float16 half4 __attribute__((ext_vector_type(4)));
typedef _Float16 half8 __attribute__((ext_vector_type(8)));
typedef float floatx4 __attribute__((ext_vector_type(4)));

#define NN 40000
#define MP 40064     // NN padded to 128 for gemm128 (padded rows: finite garbage, never read)
#define EE 160000
#define GG 512
#define HH 256
#define HD3 768
#define SCAN_NB 157   // ceil(NN/256)

__device__ inline float wave_allreduce_sum(float v) {
    #pragma unroll
    for (int off = 1; off < 64; off <<= 1) v += __shfl_xor(v, off, 64);
    return v;
}

// ---------------- mega prep: zero + go + weight transforms (all independent) ----------------
__global__ void prep_kernel(
    int* __restrict__ indeg, int* __restrict__ cursor, float* __restrict__ qh,
    float* __restrict__ cbuf,
    const int* __restrict__ batch, int* __restrict__ go,
    const float* __restrict__ proj_W, fp16* __restrict__ projWTh, fp16* __restrict__ projWTl,
    const float* __restrict__ Wn, fp16* __restrict__ WnTh, fp16* __restrict__ WnTl,
    const float* __restrict__ Ws, fp16* __restrict__ WsTh, fp16* __restrict__ WsTl,
    const float* __restrict__ Wih, const float* __restrict__ Whh,
    fp16* __restrict__ Wcombh, fp16* __restrict__ Wcombl,
    const float* __restrict__ b_ih, const float* __restrict__ b_hh, float* __restrict__ bsumv,
    const float* __restrict__ We, const float* __restrict__ Watt,
    float* __restrict__ ubuf, float* __restrict__ vabuf, float* __restrict__ vjbuf)
{
    int i = blockIdx.x * blockDim.x + threadIdx.x;
    if (i < NN) { indeg[i] = 0; cursor[i] = 0; return; }
    i -= NN;
    if (i < GG * HD3) { qh[i] = 0.f; return; }
    i -= GG * HD3;
    if (i < GG * HH) { cbuf[i] = 0.f; return; }
    i -= GG * HH;
    if (i < GG + 1) {   // go via binary search over sorted batch
        int lo = 0, hi = NN;
        while (lo < hi) { int mid = (lo + hi) >> 1; if (batch[mid] < i) lo = mid + 1; else hi = mid; }
        go[i] = lo;
        return;
    }
    i -= (GG + 1);
    if (i < 64 * HH) {   // proj transpose split [64,256] -> [256,64]
        int r = i / HH, c = i % HH;
        float v = proj_W[i];
        fp16 hv = (fp16)v;
        projWTh[(size_t)c * 64 + r] = hv;
        projWTl[(size_t)c * 64 + r] = (fp16)(v - (float)hv);
        return;
    }
    i -= 64 * HH;
    if (i < 3 * HH * HD3) {   // Wn transpose split per layer [256,768] -> [768,256]
        int l = i / (HH * HD3), rem = i % (HH * HD3), r = rem / HD3, c = rem % HD3;
        float v = Wn[i];
        fp16 hv = (fp16)v;
        WnTh[(size_t)l * HD3 * HH + (size_t)c * HH + r] = hv;
        WnTl[(size_t)l * HD3 * HH + (size_t)c * HH + r] = (fp16)(v - (float)hv);
        return;
    }
    i -= 3 * HH * HD3;
    if (i < 3 * HD3 * HH) {   // Ws transpose split per layer [768,256] -> [256,768]
        int l = i / (HD3 * HH), rem = i % (HD3 * HH), r = rem / HH, c = rem % HH;
        float v = Ws[i];
        fp16 hv = (fp16)v;
        WsTh[(size_t)l * HH * HD3 + (size_t)c * HD3 + r] = hv;
        WsTl[(size_t)l * HH * HD3 + (size_t)c * HD3 + r] = (fp16)(v - (float)hv);
        return;
    }
    i -= 3 * HD3 * HH;
    if (i < 1024 * HD3) {   // Wcomb = [W_ih | W_hh], split
        int rw = i / HD3, cl = i % HD3;
        float v = (cl < 512) ? Wih[rw * 512 + cl] : Whh[rw * 256 + (cl - 512)];
        fp16 hv = (fp16)v;
        Wcombh[i] = hv;
        Wcombl[i] = (fp16)(v - (float)hv);
        return;
    }
    i -= 1024 * HD3;
    if (i < 1024) { bsumv[i] = b_ih[i] + b_hh[i]; return; }
    i -= 1024;
    if (i < 144) {   // u[(l*3+h)*16+k]
        int l = i / 48, h = (i % 48) / 16, k = i % 16;
        float s = 0.f;
        for (int c = 0; c < 256; ++c)
            s += We[(size_t)l * 12288 + k * 768 + h * 256 + c]
               * Watt[(size_t)l * 2304 + h * 768 + 256 + c];
        ubuf[i] = s;
        return;
    }
    i -= 144;
    if (i < 2304) {   // va/vj
        int l = i / 768, rem = i % 768, h = rem / 256, c = rem % 256;
        const float* wn = Wn + ((size_t)l * 256 + c) * 768 + h * 256;
        const float* wa = Watt + (size_t)l * 2304 + h * 768;
        float sa = 0.f, sj = 0.f;
        for (int d = 0; d < 256; ++d) { float w = wn[d]; sa += w * wa[d]; sj += w * wa[512 + d]; }
        vabuf[i] = sa; vjbuf[i] = sj;
        return;
    }
}
#define PREP_TOTAL (NN + GG*HD3 + GG*HH + (GG+1) + 64*HH + 3*HH*HD3 + 3*HD3*HH + 1024*HD3 + 1024 + 144 + 2304)

// ---------------- hierarchical scan ----------------
__global__ __launch_bounds__(256) void scan1_kernel(const int* __restrict__ cnt,
    int* __restrict__ exc, int* __restrict__ bsum, int n)
{
    __shared__ int s[256];
    int tid = threadIdx.x, i = blockIdx.x * 256 + tid;
    int v = (i < n) ? cnt[i] : 0;
    s[tid] = v; __syncthreads();
    #pragma unroll
    for (int d = 1; d < 256; d <<= 1) {
        int t = (tid >= d) ? s[tid - d] : 0;
        __syncthreads();
        s[tid] += t;
        __syncthreads();
    }
    if (i < n) exc[i] = s[tid] - v;
    if (tid == 255) bsum[blockIdx.x] = s[255];
}
__global__ __launch_bounds__(256) void scan2_kernel(const int* __restrict__ bsum,
    int* __restrict__ boff, int nb)
{
    __shared__ int s[256];
    int tid = threadIdx.x;
    int v = (tid < nb) ? bsum[tid] : 0;
    s[tid] = v; __syncthreads();
    #pragma unroll
    for (int d = 1; d < 256; d <<= 1) {
        int t = (tid >= d) ? s[tid - d] : 0;
        __syncthreads();
        s[tid] += t;
        __syncthreads();
    }
    if (tid < nb) boff[tid] = s[tid] - v;
    if (tid == nb - 1) boff[nb] = s[tid];
}
__global__ __launch_bounds__(256) void scan3_kernel(int* __restrict__ exc,
    const int* __restrict__ boff, int n, int nb)
{
    int i = blockIdx.x * 256 + threadIdx.x;
    if (i < n) exc[i] += boff[blockIdx.x];
    if (i == 0) exc[n] = boff[nb];
}

// ---------------- edge CSR build ----------------
__global__ void hist_edge_kernel(const int* __restrict__ ei, int* __restrict__ indeg, int E_) {
    int e = blockIdx.x * blockDim.x + threadIdx.x;
    if (e < E_) atomicAdd(&indeg[ei[E_ + e]], 1);
}
__global__ void scatter_kernel(const int* __restrict__ ei, const float* __restrict__ eattr,
    const int* __restrict__ offs, int* __restrict__ cursor,
    int* __restrict__ src_sorted, float* __restrict__ attr_csr, int E_)
{
    int e = blockIdx.x * blockDim.x + threadIdx.x;
    if (e >= E_) return;
    int d = ei[E_ + e];
    int pos = offs[d] + atomicAdd(&cursor[d], 1);
    src_sorted[pos] = ei[e];
    const float4* sp = (const float4*)&eattr[(size_t)e * 16];
    float4* dp = (float4*)&attr_csr[(size_t)pos * 16];
    dp[0] = sp[0]; dp[1] = sp[1]; dp[2] = sp[2]; dp[3] = sp[3];
}

// ---------------- 64-tile split-fp16 GEMM (proj, gates) ----------------
template<int ASPLIT, int BIAS, int RES, int OUTF, int ACT>
__global__ __launch_bounds__(256) void gemm_s(const void* __restrict__ Av,
    const fp16* __restrict__ Bth, const fp16* __restrict__ Btl,
    void* __restrict__ Cv, const float* __restrict__ bias, const float* __restrict__ res,
    int M, int N, int K)
{
    __shared__ __align__(16) fp16 Ash[64 * 40];
    __shared__ __align__(16) fp16 Asl[64 * 40];
    __shared__ __align__(16) fp16 Bsh[64 * 40];
    __shared__ __align__(16) fp16 Bsl[64 * 40];
    const int m0 = blockIdx.x * 64, n0 = blockIdx.y * 64;
    const int t = threadIdx.x;
    const int row = t >> 2, cb = t & 3;
    const int lane = t & 63, wave = t >> 6, quad = lane >> 4, r0 = lane & 15;

    floatx4 acc[4];
    #pragma unroll
    for (int i = 0; i < 4; ++i) acc[i] = (floatx4)(0.f);

    for (int k0 = 0; k0 < K; k0 += 32) {
        if (ASPLIT) {
            const float* A = (const float*)Av;
            const float* ap = &A[(size_t)(m0 + row) * K + k0 + cb * 8];
            float4 v0 = *(const float4*)ap;
            float4 v1 = *(const float4*)(ap + 4);
            float vv[8] = {v0.x, v0.y, v0.z, v0.w, v1.x, v1.y, v1.z, v1.w};
            half8 hh, ll;
            #pragma unroll
            for (int j = 0; j < 8; ++j) {
                fp16 hv = (fp16)vv[j];
                hh[j] = hv;
                ll[j] = (fp16)(vv[j] - (float)hv);
            }
            *(half8*)&Ash[row * 40 + cb * 8] = hh;
            *(half8*)&Asl[row * 40 + cb * 8] = ll;
        } else {
            const fp16* A = (const fp16*)Av;
            *(uint4*)&Ash[row * 40 + cb * 8] = *(const uint4*)&A[(size_t)(m0 + row) * K + k0 + cb * 8];
        }
        *(uint4*)&Bsh[row * 40 + cb * 8] = *(const uint4*)&Bth[(size_t)(n0 + row) * K + k0 + cb * 8];
        *(uint4*)&Bsl[row * 40 + cb * 8] = *(const uint4*)&Btl[(size_t)(n0 + row) * K + k0 + cb * 8];
        __syncthreads();
        half8 afh = *(const half8*)&Ash[(wave * 16 + r0) * 40 + quad * 8];
        half8 afl;
        if (ASPLIT) afl = *(const half8*)&Asl[(wave * 16 + r0) * 40 + quad * 8];
        #pragma unroll
        for (int tt = 0; tt < 4; ++tt) {
            half8 bh = *(const half8*)&Bsh[(tt * 16 + r0) * 40 + quad * 8];
            half8 bl = *(const half8*)&Bsl[(tt * 16 + r0) * 40 + quad * 8];
            acc[tt] = __builtin_amdgcn_mfma_f32_16x16x32_f16(afh, bh, acc[tt], 0, 0, 0);
            if (ASPLIT) acc[tt] = __builtin_amdgcn_mfma_f32_16x16x32_f16(afl, bh, acc[tt], 0, 0, 0);
            acc[tt] = __builtin_amdgcn_mfma_f32_16x16x32_f16(afh, bl, acc[tt], 0, 0, 0);
        }
        __syncthreads();
    }
    #pragma unroll
    for (int tt = 0; tt < 4; ++tt) {
        #pragma unroll
        for (int r = 0; r < 4; ++r) {
            int m = m0 + wave * 16 + quad * 4 + r;
            int n = n0 + tt * 16 + r0;
            float v = acc[tt][r];
            if (BIAS) v += bias[n];
            if (RES) v += res[(size_t)m * N + n];
            if (ACT) v = v > 0.f ? v : expm1f(v);   // celu
            if (OUTF) ((float*)Cv)[(size_t)m * N + n] = v;
            else      ((fp16*)Cv)[(size_t)m * N + n] = (fp16)v;
        }
    }
}

// ---------------- 128-tile split-fp16 GEMM (xn, Ws) ----------------
// ASPLIT=1: A fp32 split on the fly (3 MFMA/tile). ASPLIT=0: A fp16 exact (2 MFMA/tile).
// NOTE r9 lesson: do NOT drop the AlBh pass (ASPLIT=2 regressed absmax 0.025->0.078).
template<int ASPLIT, int EPI>
__global__ __launch_bounds__(256) void gemm128(const void* __restrict__ Av,
    const fp16* __restrict__ Bth, const fp16* __restrict__ Btl,
    void* __restrict__ Cv, const float* __restrict__ bias, const float* __restrict__ res,
    int M, int N, int K)
{
    __shared__ __align__(16) fp16 AsH[128 * 40];
    __shared__ __align__(16) fp16 AsL[(ASPLIT == 1) ? 128 * 40 : 8];
    __shared__ __align__(16) fp16 BsH[128 * 40];
    __shared__ __align__(16) fp16 BsL[128 * 40];
    const int m0 = blockIdx.x * 128, n0 = blockIdx.y * 128;
    const int t = threadIdx.x;
    const int row = t >> 1, cb = (t & 1) * 16;
    const int lane = t & 63, wave = t >> 6, quad = lane >> 4, r0 = lane & 15;
    const int mb = (wave >> 1) * 64, nb = (wave & 1) * 64;

    floatx4 acc[4][4];
    #pragma unroll
    for (int i = 0; i < 4; ++i)
        #pragma unroll
        for (int j = 0; j < 4; ++j) acc[i][j] = (floatx4)(0.f);

    for (int k0 = 0; k0 < K; k0 += 32) {
        if (ASPLIT == 1) {
            const float* A = (const float*)Av;
            const float* ap = &A[(size_t)(m0 + row) * K + k0 + cb];
            #pragma unroll
            for (int u = 0; u < 2; ++u) {
                float4 v0 = *(const float4*)(ap + u * 8);
                float4 v1 = *(const float4*)(ap + u * 8 + 4);
                float vv[8] = {v0.x, v0.y, v0.z, v0.w, v1.x, v1.y, v1.z, v1.w};
                half8 hh, ll;
                #pragma unroll
                for (int j = 0; j < 8; ++j) {
                    fp16 hv = (fp16)vv[j];
                    hh[j] = hv;
                    ll[j] = (fp16)(vv[j] - (float)hv);
                }
                *(half8*)&AsH[row * 40 + cb + u * 8] = hh;
                *(half8*)&AsL[row * 40 + cb + u * 8] = ll;
            }
        } else {
            const fp16* A = (const fp16*)Av;
            const fp16* ap = &A[(size_t)(m0 + row) * K + k0 + cb];
            *(uint4*)&AsH[row * 40 + cb] = *(const uint4*)ap;
            *(uint4*)&AsH[row * 40 + cb + 8] = *(const uint4*)(ap + 8);
        }
        const fp16* bph = &Bth[(size_t)(n0 + row) * K + k0 + cb];
        *(uint4*)&BsH[row * 40 + cb] = *(const uint4*)bph;
        *(uint4*)&BsH[row * 40 + cb + 8] = *(const uint4*)(bph + 8);
        const fp16* bpl = &Btl[(size_t)(n0 + row) * K + k0 + cb];
        *(uint4*)&BsL[row * 40 + cb] = *(const uint4*)bpl;
        *(uint4*)&BsL[row * 40 + cb + 8] = *(const uint4*)(bpl + 8);
        __syncthreads();
        half8 afh[4], afl[4], bfh[4], bfl[4];
        #pragma unroll
        for (int i = 0; i < 4; ++i) {
            afh[i] = *(const half8*)&AsH[(mb + i * 16 + r0) * 40 + quad * 8];
            if (ASPLIT == 1) afl[i] = *(const half8*)&AsL[(mb + i * 16 + r0) * 40 + quad * 8];
            bfh[i] = *(const half8*)&BsH[(nb + i * 16 + r0) * 40 + quad * 8];
            bfl[i] = *(const half8*)&BsL[(nb + i * 16 + r0) * 40 + quad * 8];
        }
        #pragma unroll
        for (int mi = 0; mi < 4; ++mi)
            #pragma unroll
            for (int ni = 0; ni < 4; ++ni) {
                acc[mi][ni] = __builtin_amdgcn_mfma_f32_16x16x32_f16(afh[mi], bfh[ni], acc[mi][ni], 0, 0, 0);
                if (ASPLIT == 1) acc[mi][ni] = __builtin_amdgcn_mfma_f32_16x16x32_f16(afl[mi], bfh[ni], acc[mi][ni], 0, 0, 0);
                acc[mi][ni] = __builtin_amdgcn_mfma_f32_16x16x32_f16(afh[mi], bfl[ni], acc[mi][ni], 0, 0, 0);
            }
        __syncthreads();
    }
    #pragma unroll
    for (int mi = 0; mi < 4; ++mi)
        #pragma unroll
        for (int ni = 0; ni < 4; ++ni)
            #pragma unroll
            for (int r = 0; r < 4; ++r) {
                int m = m0 + mb + mi * 16 + quad * 4 + r;
                int n = n0 + nb + ni * 16 + r0;
                float v = acc[mi][ni][r];
                if (EPI) {
                    v += bias[n] + res[(size_t)m * N + n];
                    ((float*)Cv)[(size_t)m * N + n] = v;
                } else {
                    ((fp16*)Cv)[(size_t)m * N + n] = (fp16)v;
                }
            }
}

// ---------------- exact logit parts ----------------
__global__ void tl_kernel(const float* __restrict__ attr, const float* __restrict__ u,
                          float* __restrict__ tl, int E_) {
    int p = blockIdx.x * blockDim.x + threadIdx.x;
    if (p >= E_) return;
    float a[16];
    #pragma unroll
    for (int k = 0; k < 16; ++k) a[k] = attr[(size_t)p * 16 + k];
    #pragma unroll
    for (int l = 0; l < 3; ++l)
        #pragma unroll
        for (int h = 0; h < 3; ++h) {
            float s = 0.f;
            #pragma unroll
            for (int k = 0; k < 16; ++k) s += a[k] * u[(l * 3 + h) * 16 + k];
            tl[(size_t)l * EE * 3 + p * 3 + h] = s;
        }
}
__global__ __launch_bounds__(256) void lilj_kernel(const float* __restrict__ outF,
    const float* __restrict__ va, const float* __restrict__ vj,
    float* __restrict__ li, float* __restrict__ lj, int Nn)
{
    int wid = blockIdx.x * 4 + (threadIdx.x >> 6);
    int lane = threadIdx.x & 63;
    int nw = gridDim.x * 4;
    float4 vah[3], vjh[3];
    #pragma unroll
    for (int h = 0; h < 3; ++h) {
        vah[h] = *(const float4*)&va[h * 256 + lane * 4];
        vjh[h] = *(const float4*)&vj[h * 256 + lane * 4];
    }
    for (int n = wid; n < Nn; n += nw) {
        float4 o = *(const float4*)&outF[(size_t)n * HH + lane * 4];
        #pragma unroll
        for (int h = 0; h < 3; ++h) {
            float sa = o.x * vah[h].x + o.y * vah[h].y + o.z * vah[h].z + o.w * vah[h].w;
            float sj = o.x * vjh[h].x + o.y * vjh[h].y + o.z * vjh[h].z + o.w * vjh[h].w;
            sa = wave_allreduce_sum(sa);
            sj = wave_allreduce_sum(sj);
            if (lane == 0) { li[n * 3 + h] = sa; lj[n * 3 + h] = sj; }
        }
    }
}

// ---------------- attention weights (exact logits -> normalized alpha) ----------------
__global__ __launch_bounds__(256) void alpha_kernel(const int* __restrict__ src_sorted,
    const int* __restrict__ offs, const float* __restrict__ tl,
    const float* __restrict__ li, const float* __restrict__ lj,
    float* __restrict__ alpha, int Nn)
{
    int idx = blockIdx.x * blockDim.x + threadIdx.x;
    if (idx >= Nn * 3) return;
    int node = idx / 3, h = idx % 3;
    int p0 = offs[node], p1 = offs[node + 1];
    if (p0 >= p1) return;
    float base = li[node * 3 + h];
    float m = -1e30f;
    for (int p = p0; p < p1; ++p) {
        float l = base + tl[p * 3 + h] + lj[src_sorted[p] * 3 + h];
        l = l >= 0.f ? l : 0.2f * l;
        m = fmaxf(m, l);
    }
    float s = 0.f;
    for (int p = p0; p < p1; ++p) {
        float l = base + tl[p * 3 + h] + lj[src_sorted[p] * 3 + h];
        l = l >= 0.f ? l : 0.2f * l;
        float w = expf(l - m);
        alpha[p * 3 + h] = w;
        s += w;
    }
    float inv = 1.f / (s + 1e-16f);
    for (int p = p0; p < p1; ++p) alpha[p * 3 + h] *= inv;
}

// ---------------- edge message kernel (r8 numerics; pairwise software pipeline) ----------------
// Per acc[j], contributions added in CSR order p, p+1, ... -> bit-identical to serial loop.
__global__ __launch_bounds__(256) void edge_kernel(
    const fp16* __restrict__ xn, const float* __restrict__ attr,
    const int* __restrict__ src_sorted, const int* __restrict__ offs,
    const float* __restrict__ alpha, const float* __restrict__ We,
    fp16* __restrict__ aggr, int Nn)
{
    const int gw = blockIdx.x * 4 + (threadIdx.x >> 6);   // 3750 blocks -> 15000 waves
    const int lane = threadIdx.x & 63;
    const int h = gw % 3;
    const int slot = gw / 3;                              // 0..4999
    const int xoff = h * 256 + lane * 4;

    float WeR[4][16];
    #pragma unroll
    for (int j = 0; j < 4; ++j)
        #pragma unroll
        for (int k = 0; k < 16; ++k)
            WeR[j][k] = We[k * 768 + h * 256 + lane * 4 + j];

    for (int node = slot; node < Nn; node += 5000) {
        float acc[4] = {0.f, 0.f, 0.f, 0.f};
        int p0 = offs[node], p1 = offs[node + 1];
        int p = p0;
        // pairs: both xn gathers issued before either compute (2x MLP per wave)
        for (; p + 2 <= p1; p += 2) {
            int s0 = src_sorted[p], s1 = src_sorted[p + 1];
            half4 x0 = *(const half4*)&xn[(size_t)s0 * HD3 + xoff];
            half4 x1 = *(const half4*)&xn[(size_t)s1 * HD3 + xoff];
            float a0 = alpha[p * 3 + h];
            float a1 = alpha[(p + 1) * 3 + h];
            const float4* ap0 = (const float4*)&attr[(size_t)p * 16];
            const float4* ap1 = (const float4*)&attr[(size_t)(p + 1) * 16];
            float4 u0 = ap0[0], u1 = ap0[1], u2 = ap0[2], u3 = ap0[3];
            float4 w0 = ap1[0], w1 = ap1[1], w2 = ap1[2], w3 = ap1[3];
            float av0[16] = {u0.x, u0.y, u0.z, u0.w, u1.x, u1.y, u1.z, u1.w,
                             u2.x, u2.y, u2.z, u2.w, u3.x, u3.y, u3.z, u3.w};
            float av1[16] = {w0.x, w0.y, w0.z, w0.w, w1.x, w1.y, w1.z, w1.w,
                             w2.x, w2.y, w2.z, w2.w, w3.x, w3.y, w3.z, w3.w};
            #pragma unroll
            for (int j = 0; j < 4; ++j) {
                float e0 = 0.f, e1 = 0.f;
                #pragma unroll
                for (int k = 0; k < 16; ++k) {
                    e0 += av0[k] * WeR[j][k];
                    e1 += av1[k] * WeR[j][k];
                }
                acc[j] += (a0 * (float)x0[j]) * e0;   // edge p first
                acc[j] += (a1 * (float)x1[j]) * e1;   // then edge p+1
            }
        }
        if (p < p1) {   // tail edge
            int s = src_sorted[p];
            float a = alpha[p * 3 + h];
            half4 xr = *(const half4*)&xn[(size_t)s * HD3 + xoff];
            const float4* ap = (const float4*)&attr[(size_t)p * 16];
            float4 q0 = ap[0], q1 = ap[1], q2 = ap[2], q3 = ap[3];
            float av[16] = {q0.x, q0.y, q0.z, q0.w, q1.x, q1.y, q1.z, q1.w,
                            q2.x, q2.y, q2.z, q2.w, q3.x, q3.y, q3.z, q3.w};
            #pragma unroll
            for (int j = 0; j < 4; ++j) {
                float e = 0.f;
                #pragma unroll
                for (int k = 0; k < 16; ++k) e += av[k] * WeR[j][k];
                acc[j] += (a * (float)xr[j]) * e;
            }
        }
        half4 o;
        #pragma unroll
        for (int j = 0; j < 4; ++j) o[j] = (fp16)acc[j];
        *(half4*)&aggr[(size_t)node * HD3 + xoff] = o;
    }
}

// ---------------- Set2Set: fused LSTM cell + e + segment-softmax + r (block per graph) ----------------
// LSTM expressions and e/r summation orders identical to the split kernels.
__global__ __launch_bounds__(256) void lstm_er_kernel(const float* __restrict__ gates,
    float* __restrict__ c, const int* __restrict__ go,
    const float* __restrict__ outf, float* __restrict__ qh)
{
    __shared__ float hh[256];
    __shared__ float esh[1024];
    __shared__ float red[256];
    int g = blockIdx.x, tid = threadIdx.x;
    // LSTM cell for (g, tid)
    const float* gr = gates + (size_t)g * 1024;
    float gi = gr[tid], gf = gr[256 + tid], gc = gr[512 + tid], gov = gr[768 + tid];
    float si = 1.f / (1.f + expf(-gi));
    float sf = 1.f / (1.f + expf(-gf));
    float so = 1.f / (1.f + expf(-gov));
    int cidx = g * HH + tid;
    float cn = sf * c[cidx] + si * tanhf(gc);
    float hn = so * tanhf(cn);
    c[cidx] = cn;
    qh[(size_t)g * HD3 + tid] = hn;         // q_star[:, :H]
    qh[(size_t)g * HD3 + 512 + tid] = hn;   // h slot for W_hh
    hh[tid] = hn;
    int lane = tid & 63, wv = tid >> 6;
    int lo = go[g], hi = go[g + 1];
    float m = -1e30f, ssum = 0.f, racc = 0.f;
    __syncthreads();
    float4 hv = *(const float4*)&hh[lane * 4];
    for (int base = lo; base < hi; base += 1024) {
        int cnt = min(1024, hi - base);
        for (int i = wv; i < cnt; i += 4) {
            const float4 ov = *(const float4*)&outf[(size_t)(base + i) * HH + lane * 4];
            float pp = ov.x * hv.x + ov.y * hv.y + ov.z * hv.z + ov.w * hv.w;
            pp = wave_allreduce_sum(pp);
            if (lane == 0) esh[i] = pp;
        }
        __syncthreads();
        float lm = -1e30f;
        for (int i = tid; i < cnt; i += 256) lm = fmaxf(lm, esh[i]);
        red[tid] = lm; __syncthreads();
        for (int s = 128; s > 0; s >>= 1) { if (tid < s) red[tid] = fmaxf(red[tid], red[tid + s]); __syncthreads(); }
        float cm = red[0]; __syncthreads();
        float mn = fmaxf(m, cm);
        float scale = expf(m - mn);
        float ls = 0.f;
        for (int i = tid; i < cnt; i += 256) { float w = expf(esh[i] - mn); esh[i] = w; ls += w; }
        red[tid] = ls; __syncthreads();
        for (int s = 128; s > 0; s >>= 1) { if (tid < s) red[tid] += red[tid + s]; __syncthreads(); }
        float csum = red[0]; __syncthreads();
        ssum = ssum * scale + csum;
        racc *= scale;
        for (int i = 0; i < cnt; ++i)
            racc += esh[i] * outf[(size_t)(base + i) * HH + tid];
        m = mn;
        __syncthreads();
    }
    qh[(size_t)g * HD3 + 256 + tid] = racc / (ssum + 1e-16f);
}

// ---------------- MLP head (fp32) ----------------
__global__ __launch_bounds__(256) void head_kernel(const float* __restrict__ qh,
    const float* __restrict__ W1, const float* __restrict__ b1,
    const float* __restrict__ lng, const float* __restrict__ lnb,
    const float* __restrict__ W2, const float* __restrict__ b2,
    float* __restrict__ outp)
{
    __shared__ float q[512];
    __shared__ float red[256];
    __shared__ float yl[256];
    int g = blockIdx.x, tid = threadIdx.x;
    q[tid] = qh[(size_t)g * HD3 + tid];
    q[tid + 256] = qh[(size_t)g * HD3 + 256 + tid];
    __syncthreads();
    float y = b1[tid];
    for (int k = 0; k < 512; ++k) y += q[k] * W1[k * 256 + tid];
    red[tid] = y; __syncthreads();
    for (int s = 128; s > 0; s >>= 1) { if (tid < s) red[tid] += red[tid + s]; __syncthreads(); }
    float mu = red[0] * (1.f / 256.f); __syncthreads();
    red[tid] = y * y; __syncthreads();
    for (int s = 128; s > 0; s >>= 1) { if (tid < s) red[tid] += red[tid + s]; __syncthreads(); }
    float var = red[0] * (1.f / 256.f) - mu * mu; __syncthreads();
    float yn = (y - mu) * rsqrtf(var + 1e-5f) * lng[tid] + lnb[tid];
    yl[tid] = fmaxf(yn, 0.f);
    __syncthreads();
    if (tid < 12) {
        float a = b2[tid];
        for (int d = 0; d < 256; ++d) a += yl[d] * W2[d * 12 + tid];
        outp[g * 12 + tid] = a;
    }
}

extern "C" void kernel_launch(void* const* d_in, const int* in_sizes, int n_in,
                              void* d_out, int out_size, void* d_ws, size_t ws_size,
                              hipStream_t stream)
{
    const float* x         = (const float*)d_in[0];
    const float* edge_attr = (const float*)d_in[1];
    const int*   edge_index= (const int*)d_in[2];
    const int*   batch     = (const int*)d_in[3];
    const float* proj_W    = (const float*)d_in[4];
    const float* proj_b    = (const float*)d_in[5];
    const float* Wn        = (const float*)d_in[6];
    const float* We        = (const float*)d_in[7];
    const float* Watt      = (const float*)d_in[8];
    const float* Ws        = (const float*)d_in[9];
    const float* bl        = (const float*)d_in[10];
    const float* W_ih      = (const float*)d_in[11];
    const float* W_hh      = (const float*)d_in[12];
    const float* b_ih      = (const float*)d_in[13];
    const float* b_hh      = (const float*)d_in[14];
    const float* mlp_W1    = (const float*)d_in[15];
    const float* mlp_b1    = (const float*)d_in[16];
    const float* ln_g      = (const float*)d_in[17];
    const float* ln_b      = (const float*)d_in[18];
    const float* mlp_W2    = (const float*)d_in[19];
    const float* mlp_b2    = (const float*)d_in[20];
    (void)in_sizes; (void)n_in; (void)out_size; (void)ws_size;

    char* p = (char*)d_ws;
    auto alloc = [&](size_t bytes) { char* r = p; p += (bytes + 255) & ~(size_t)255; return r; };

    // total ~199 MB (206 MB proven safe on this harness)
    int*   offs    = (int*)alloc((size_t)(NN + 1) * 4);
    int*   indeg   = (int*)alloc((size_t)NN * 4);
    int*   cursor  = (int*)alloc((size_t)NN * 4);
    int*   go      = (int*)alloc((size_t)(GG + 1) * 4);
    int*   bsum    = (int*)alloc((size_t)SCAN_NB * 4);
    int*   boff    = (int*)alloc((size_t)(SCAN_NB + 1) * 4);
    float* qh      = (float*)alloc((size_t)GG * HD3 * 4);
    float* gates   = (float*)alloc((size_t)GG * 1024 * 4);
    float* cbuf    = (float*)alloc((size_t)GG * HH * 4);
    float* bsumv   = (float*)alloc((size_t)1024 * 4);
    float* ubuf    = (float*)alloc((size_t)144 * 4);
    float* vabuf   = (float*)alloc((size_t)2304 * 4);
    float* vjbuf   = (float*)alloc((size_t)2304 * 4);
    float* libuf   = (float*)alloc((size_t)NN * 3 * 4);
    float* ljbuf   = (float*)alloc((size_t)NN * 3 * 4);
    float* albuf   = (float*)alloc((size_t)EE * 3 * 4);
    fp16*  projWTh = (fp16*)alloc((size_t)HH * 64 * 2);
    fp16*  projWTl = (fp16*)alloc((size_t)HH * 64 * 2);
    fp16*  WnTh    = (fp16*)alloc((size_t)3 * HD3 * HH * 2);
    fp16*  WnTl    = (fp16*)alloc((size_t)3 * HD3 * HH * 2);
    fp16*  WsTh    = (fp16*)alloc((size_t)3 * HH * HD3 * 2);
    fp16*  WsTl    = (fp16*)alloc((size_t)3 * HH * HD3 * 2);
    fp16*  Wcombh  = (fp16*)alloc((size_t)1024 * HD3 * 2);
    fp16*  Wcombl  = (fp16*)alloc((size_t)1024 * HD3 * 2);
    int*   src_srt = (int*)alloc((size_t)EE * 4);
    float* attr_csr= (float*)alloc((size_t)EE * 16 * 4);
    float* tlbuf   = (float*)alloc((size_t)3 * EE * 3 * 4);
    float* outF32  = (float*)alloc((size_t)MP * HH * 4);
    fp16*  xn      = (fp16*)alloc((size_t)MP * HD3 * 2);
    fp16*  aggr    = (fp16*)alloc((size_t)MP * HD3 * 2);

    // one mega-prep launch: zeros, go, all weight transforms, u/va/vj
    prep_kernel<<<(PREP_TOTAL + 255) / 256, 256, 0, stream>>>(
        indeg, cursor, qh, cbuf, batch, go,
        proj_W, projWTh, projWTl, Wn, WnTh, WnTl, Ws, WsTh, WsTl,
        W_ih, W_hh, Wcombh, Wcombl, b_ih, b_hh, bsumv,
        We, Watt, ubuf, vabuf, vjbuf);

    hist_edge_kernel<<<(EE + 255) / 256, 256, 0, stream>>>(edge_index, indeg, EE);
    scan1_kernel<<<SCAN_NB, 256, 0, stream>>>(indeg, offs, bsum, NN);
    scan2_kernel<<<1, 256, 0, stream>>>(bsum, boff, SCAN_NB);
    scan3_kernel<<<SCAN_NB, 256, 0, stream>>>(offs, boff, NN, SCAN_NB);
    scatter_kernel<<<(EE + 255) / 256, 256, 0, stream>>>(edge_index, edge_attr, offs, cursor,
        src_srt, attr_csr, EE);
    tl_kernel<<<(EE + 255) / 256, 256, 0, stream>>>(attr_csr, ubuf, tlbuf, EE);

    // out = celu(x @ proj_W + proj_b): 64-tile split-3 MFMA, fp32 out
    gemm_s<1, 1, 0, 1, 1><<<dim3(NN / 64, HH / 64), 256, 0, stream>>>(
        x, projWTh, projWTl, outF32, proj_b, nullptr, NN, HH, 64);

    for (int l = 0; l < 3; ++l) {
        lilj_kernel<<<2500, 256, 0, stream>>>(outF32, vabuf + l * 768, vjbuf + l * 768,
            libuf, ljbuf, NN);
        alpha_kernel<<<(NN * 3 + 255) / 256, 256, 0, stream>>>(src_srt, offs,
            tlbuf + (size_t)l * EE * 3, libuf, ljbuf, albuf, NN);
        gemm128<1, 0><<<dim3(MP / 128, HD3 / 128), 256, 0, stream>>>(
            outF32, WnTh + (size_t)l * HD3 * HH, WnTl + (size_t)l * HD3 * HH,
            xn, nullptr, nullptr, MP, HD3, HH);
        edge_kernel<<<3750, 256, 0, stream>>>(xn, attr_csr, src_srt, offs,
            albuf, We + (size_t)l * 12288, aggr, NN);
        gemm128<0, 1><<<dim3(MP / 128, HH / 128), 256, 0, stream>>>(
            aggr, WsTh + (size_t)l * HH * HD3, WsTl + (size_t)l * HH * HD3,
            outF32, bl + (size_t)l * HH, outF32, MP, HH, HD3);
    }

    for (int s = 0; s < 6; ++s) {
        gemm_s<1, 1, 0, 1, 0><<<dim3(GG / 64, 1024 / 64), 256, 0, stream>>>(
            qh, Wcombh, Wcombl, gates, bsumv, nullptr, GG, 1024, HD3);
        lstm_er_kernel<<<GG, 256, 0, stream>>>(gates, cbuf, go, outF32, qh);
    }

    head_kernel<<<GG, 256, 0, stream>>>(qh, mlp_W1, mlp_b1, ln_g, ln_b, mlp_W2, mlp_b2, (float*)d_out);
}

// Round 12
// 1404.028 us; speedup vs baseline: 1.0922x; 1.0922x over previous
//
#include <hip/hip_runtime.h>

typedef _Float16 fp16;
typedef _Float16 half4 __attribute__((ext_vector_type(4)));
typedef _Float16 half8 __attribute__((ext_vector_type(8)));
typedef float floatx4 __attribute__((ext_vector_type(4)));

#define NN 40000
#define MP 40064     // NN padded to 128 for gemm128 (padded rows: finite garbage, never read)
#define EE 160000
#define GG 512
#define HH 256
#define HD3 768
#define SCAN_NB 157   // ceil(NN/256)

__device__ inline float wave_allreduce_sum(float v) {
    #pragma unroll
    for (int off = 1; off < 64; off <<= 1) v += __shfl_xor(v, off, 64);
    return v;
}

// ---------------- mega prep: zero + go + weight transforms (all independent) ----------------
__global__ void prep_kernel(
    int* __restrict__ indeg, int* __restrict__ cursor, float* __restrict__ qh,
    float* __restrict__ cbuf,
    const int* __restrict__ batch, int* __restrict__ go,
    const float* __restrict__ proj_W, fp16* __restrict__ projWTh, fp16* __restrict__ projWTl,
    const float* __restrict__ Wn, fp16* __restrict__ WnTh, fp16* __restrict__ WnTl,
    const float* __restrict__ Ws, fp16* __restrict__ WsTh, fp16* __restrict__ WsTl,
    const float* __restrict__ Wih, const float* __restrict__ Whh,
    fp16* __restrict__ Wcombh, fp16* __restrict__ Wcombl,
    const float* __restrict__ b_ih, const float* __restrict__ b_hh, float* __restrict__ bsumv,
    const float* __restrict__ We, const float* __restrict__ Watt,
    float* __restrict__ ubuf, float* __restrict__ vabuf, float* __restrict__ vjbuf)
{
    int i = blockIdx.x * blockDim.x + threadIdx.x;
    if (i < NN) { indeg[i] = 0; cursor[i] = 0; return; }
    i -= NN;
    if (i < GG * 512) { qh[i] = 0.f; return; }
    i -= GG * 512;
    if (i < GG * HH) { cbuf[i] = 0.f; return; }
    i -= GG * HH;
    if (i < GG + 1) {   // go via binary search over sorted batch
        int lo = 0, hi = NN;
        while (lo < hi) { int mid = (lo + hi) >> 1; if (batch[mid] < i) lo = mid + 1; else hi = mid; }
        go[i] = lo;
        return;
    }
    i -= (GG + 1);
    if (i < 64 * HH) {   // proj transpose split [64,256] -> [256,64]
        int r = i / HH, c = i % HH;
        float v = proj_W[i];
        fp16 hv = (fp16)v;
        projWTh[(size_t)c * 64 + r] = hv;
        projWTl[(size_t)c * 64 + r] = (fp16)(v - (float)hv);
        return;
    }
    i -= 64 * HH;
    if (i < 3 * HH * HD3) {   // Wn transpose split per layer [256,768] -> [768,256]
        int l = i / (HH * HD3), rem = i % (HH * HD3), r = rem / HD3, c = rem % HD3;
        float v = Wn[i];
        fp16 hv = (fp16)v;
        WnTh[(size_t)l * HD3 * HH + (size_t)c * HH + r] = hv;
        WnTl[(size_t)l * HD3 * HH + (size_t)c * HH + r] = (fp16)(v - (float)hv);
        return;
    }
    i -= 3 * HH * HD3;
    if (i < 3 * HD3 * HH) {   // Ws transpose split per layer [768,256] -> [256,768]
        int l = i / (HD3 * HH), rem = i % (HD3 * HH), r = rem / HH, c = rem % HH;
        float v = Ws[i];
        fp16 hv = (fp16)v;
        WsTh[(size_t)l * HH * HD3 + (size_t)c * HD3 + r] = hv;
        WsTl[(size_t)l * HH * HD3 + (size_t)c * HD3 + r] = (fp16)(v - (float)hv);
        return;
    }
    i -= 3 * HD3 * HH;
    if (i < 1024 * 512) {   // Wcomb2 = [Wih_h + Whh | Wih_r]  (K folded 768->512, fp32-exact sum)
        int rw = i / 512, cl = i % 512;
        float v = Wih[rw * 512 + cl] + (cl < 256 ? Whh[rw * 256 + cl] : 0.f);
        fp16 hv = (fp16)v;
        Wcombh[i] = hv;
        Wcombl[i] = (fp16)(v - (float)hv);
        return;
    }
    i -= 1024 * 512;
    if (i < 1024) { bsumv[i] = b_ih[i] + b_hh[i]; return; }
    i -= 1024;
    if (i < 144) {   // u[(l*3+h)*16+k]
        int l = i / 48, h = (i % 48) / 16, k = i % 16;
        float s = 0.f;
        for (int c = 0; c < 256; ++c)
            s += We[(size_t)l * 12288 + k * 768 + h * 256 + c]
               * Watt[(size_t)l * 2304 + h * 768 + 256 + c];
        ubuf[i] = s;
        return;
    }
    i -= 144;
    if (i < 2304) {   // va/vj
        int l = i / 768, rem = i % 768, h = rem / 256, c = rem % 256;
        const float* wn = Wn + ((size_t)l * 256 + c) * 768 + h * 256;
        const float* wa = Watt + (size_t)l * 2304 + h * 768;
        float sa = 0.f, sj = 0.f;
        for (int d = 0; d < 256; ++d) { float w = wn[d]; sa += w * wa[d]; sj += w * wa[512 + d]; }
        vabuf[i] = sa; vjbuf[i] = sj;
        return;
    }
}
#define PREP_TOTAL (NN + GG*512 + GG*HH + (GG+1) + 64*HH + 3*HH*HD3 + 3*HD3*HH + 1024*512 + 1024 + 144 + 2304)

// ---------------- hierarchical scan ----------------
__global__ __launch_bounds__(256) void scan1_kernel(const int* __restrict__ cnt,
    int* __restrict__ exc, int* __restrict__ bsum, int n)
{
    __shared__ int s[256];
    int tid = threadIdx.x, i = blockIdx.x * 256 + tid;
    int v = (i < n) ? cnt[i] : 0;
    s[tid] = v; __syncthreads();
    #pragma unroll
    for (int d = 1; d < 256; d <<= 1) {
        int t = (tid >= d) ? s[tid - d] : 0;
        __syncthreads();
        s[tid] += t;
        __syncthreads();
    }
    if (i < n) exc[i] = s[tid] - v;
    if (tid == 255) bsum[blockIdx.x] = s[255];
}
__global__ __launch_bounds__(256) void scan2_kernel(const int* __restrict__ bsum,
    int* __restrict__ boff, int nb)
{
    __shared__ int s[256];
    int tid = threadIdx.x;
    int v = (tid < nb) ? bsum[tid] : 0;
    s[tid] = v; __syncthreads();
    #pragma unroll
    for (int d = 1; d < 256; d <<= 1) {
        int t = (tid >= d) ? s[tid - d] : 0;
        __syncthreads();
        s[tid] += t;
        __syncthreads();
    }
    if (tid < nb) boff[tid] = s[tid] - v;
    if (tid == nb - 1) boff[nb] = s[tid];
}
__global__ __launch_bounds__(256) void scan3_kernel(int* __restrict__ exc,
    const int* __restrict__ boff, int n, int nb)
{
    int i = blockIdx.x * 256 + threadIdx.x;
    if (i < n) exc[i] += boff[blockIdx.x];
    if (i == 0) exc[n] = boff[nb];
}

// ---------------- edge CSR build ----------------
__global__ void hist_edge_kernel(const int* __restrict__ ei, int* __restrict__ indeg, int E_) {
    int e = blockIdx.x * blockDim.x + threadIdx.x;
    if (e < E_) atomicAdd(&indeg[ei[E_ + e]], 1);
}
__global__ void scatter_kernel(const int* __restrict__ ei, const float* __restrict__ eattr,
    const int* __restrict__ offs, int* __restrict__ cursor,
    int* __restrict__ src_sorted, float* __restrict__ attr_csr, int E_)
{
    int e = blockIdx.x * blockDim.x + threadIdx.x;
    if (e >= E_) return;
    int d = ei[E_ + e];
    int pos = offs[d] + atomicAdd(&cursor[d], 1);
    src_sorted[pos] = ei[e];
    const float4* sp = (const float4*)&eattr[(size_t)e * 16];
    float4* dp = (float4*)&attr_csr[(size_t)pos * 16];
    dp[0] = sp[0]; dp[1] = sp[1]; dp[2] = sp[2]; dp[3] = sp[3];
}

// ---------------- 64-tile split-fp16 GEMM (proj, gates) ----------------
template<int ASPLIT, int BIAS, int RES, int OUTF, int ACT>
__global__ __launch_bounds__(256) void gemm_s(const void* __restrict__ Av,
    const fp16* __restrict__ Bth, const fp16* __restrict__ Btl,
    void* __restrict__ Cv, const float* __restrict__ bias, const float* __restrict__ res,
    int M, int N, int K)
{
    __shared__ __align__(16) fp16 Ash[64 * 40];
    __shared__ __align__(16) fp16 Asl[64 * 40];
    __shared__ __align__(16) fp16 Bsh[64 * 40];
    __shared__ __align__(16) fp16 Bsl[64 * 40];
    const int m0 = blockIdx.x * 64, n0 = blockIdx.y * 64;
    const int t = threadIdx.x;
    const int row = t >> 2, cb = t & 3;
    const int lane = t & 63, wave = t >> 6, quad = lane >> 4, r0 = lane & 15;

    floatx4 acc[4];
    #pragma unroll
    for (int i = 0; i < 4; ++i) acc[i] = (floatx4)(0.f);

    for (int k0 = 0; k0 < K; k0 += 32) {
        if (ASPLIT) {
            const float* A = (const float*)Av;
            const float* ap = &A[(size_t)(m0 + row) * K + k0 + cb * 8];
            float4 v0 = *(const float4*)ap;
            float4 v1 = *(const float4*)(ap + 4);
            float vv[8] = {v0.x, v0.y, v0.z, v0.w, v1.x, v1.y, v1.z, v1.w};
            half8 hh, ll;
            #pragma unroll
            for (int j = 0; j < 8; ++j) {
                fp16 hv = (fp16)vv[j];
                hh[j] = hv;
                ll[j] = (fp16)(vv[j] - (float)hv);
            }
            *(half8*)&Ash[row * 40 + cb * 8] = hh;
            *(half8*)&Asl[row * 40 + cb * 8] = ll;
        } else {
            const fp16* A = (const fp16*)Av;
            *(uint4*)&Ash[row * 40 + cb * 8] = *(const uint4*)&A[(size_t)(m0 + row) * K + k0 + cb * 8];
        }
        *(uint4*)&Bsh[row * 40 + cb * 8] = *(const uint4*)&Bth[(size_t)(n0 + row) * K + k0 + cb * 8];
        *(uint4*)&Bsl[row * 40 + cb * 8] = *(const uint4*)&Btl[(size_t)(n0 + row) * K + k0 + cb * 8];
        __syncthreads();
        half8 afh = *(const half8*)&Ash[(wave * 16 + r0) * 40 + quad * 8];
        half8 afl;
        if (ASPLIT) afl = *(const half8*)&Asl[(wave * 16 + r0) * 40 + quad * 8];
        #pragma unroll
        for (int tt = 0; tt < 4; ++tt) {
            half8 bh = *(const half8*)&Bsh[(tt * 16 + r0) * 40 + quad * 8];
            half8 bl = *(const half8*)&Bsl[(tt * 16 + r0) * 40 + quad * 8];
            acc[tt] = __builtin_amdgcn_mfma_f32_16x16x32_f16(afh, bh, acc[tt], 0, 0, 0);
            if (ASPLIT) acc[tt] = __builtin_amdgcn_mfma_f32_16x16x32_f16(afl, bh, acc[tt], 0, 0, 0);
            acc[tt] = __builtin_amdgcn_mfma_f32_16x16x32_f16(afh, bl, acc[tt], 0, 0, 0);
        }
        __syncthreads();
    }
    #pragma unroll
    for (int tt = 0; tt < 4; ++tt) {
        #pragma unroll
        for (int r = 0; r < 4; ++r) {
            int m = m0 + wave * 16 + quad * 4 + r;
            int n = n0 + tt * 16 + r0;
            float v = acc[tt][r];
            if (BIAS) v += bias[n];
            if (RES) v += res[(size_t)m * N + n];
            if (ACT) v = v > 0.f ? v : expm1f(v);   // celu
            if (OUTF) ((float*)Cv)[(size_t)m * N + n] = v;
            else      ((fp16*)Cv)[(size_t)m * N + n] = (fp16)v;
        }
    }
}

// ---------------- 128-tile split-fp16 GEMM (xn, Ws) ----------------
// NOTE r9 lesson: do NOT drop the AlBh pass (ASPLIT=2 regressed absmax 0.025->0.078).
template<int ASPLIT, int EPI>
__global__ __launch_bounds__(256) void gemm128(const void* __restrict__ Av,
    const fp16* __restrict__ Bth, const fp16* __restrict__ Btl,
    void* __restrict__ Cv, const float* __restrict__ bias, const float* __restrict__ res,
    int M, int N, int K)
{
    __shared__ __align__(16) fp16 AsH[128 * 40];
    __shared__ __align__(16) fp16 AsL[(ASPLIT == 1) ? 128 * 40 : 8];
    __shared__ __align__(16) fp16 BsH[128 * 40];
    __shared__ __align__(16) fp16 BsL[128 * 40];
    const int m0 = blockIdx.x * 128, n0 = blockIdx.y * 128;
    const int t = threadIdx.x;
    const int row = t >> 1, cb = (t & 1) * 16;
    const int lane = t & 63, wave = t >> 6, quad = lane >> 4, r0 = lane & 15;
    const int mb = (wave >> 1) * 64, nb = (wave & 1) * 64;

    floatx4 acc[4][4];
    #pragma unroll
    for (int i = 0; i < 4; ++i)
        #pragma unroll
        for (int j = 0; j < 4; ++j) acc[i][j] = (floatx4)(0.f);

    for (int k0 = 0; k0 < K; k0 += 32) {
        if (ASPLIT == 1) {
            const float* A = (const float*)Av;
            const float* ap = &A[(size_t)(m0 + row) * K + k0 + cb];
            #pragma unroll
            for (int u = 0; u < 2; ++u) {
                float4 v0 = *(const float4*)(ap + u * 8);
                float4 v1 = *(const float4*)(ap + u * 8 + 4);
                float vv[8] = {v0.x, v0.y, v0.z, v0.w, v1.x, v1.y, v1.z, v1.w};
                half8 hh, ll;
                #pragma unroll
                for (int j = 0; j < 8; ++j) {
                    fp16 hv = (fp16)vv[j];
                    hh[j] = hv;
                    ll[j] = (fp16)(vv[j] - (float)hv);
                }
                *(half8*)&AsH[row * 40 + cb + u * 8] = hh;
                *(half8*)&AsL[row * 40 + cb + u * 8] = ll;
            }
        } else {
            const fp16* A = (const fp16*)Av;
            const fp16* ap = &A[(size_t)(m0 + row) * K + k0 + cb];
            *(uint4*)&AsH[row * 40 + cb] = *(const uint4*)ap;
            *(uint4*)&AsH[row * 40 + cb + 8] = *(const uint4*)(ap + 8);
        }
        const fp16* bph = &Bth[(size_t)(n0 + row) * K + k0 + cb];
        *(uint4*)&BsH[row * 40 + cb] = *(const uint4*)bph;
        *(uint4*)&BsH[row * 40 + cb + 8] = *(const uint4*)(bph + 8);
        const fp16* bpl = &Btl[(size_t)(n0 + row) * K + k0 + cb];
        *(uint4*)&BsL[row * 40 + cb] = *(const uint4*)bpl;
        *(uint4*)&BsL[row * 40 + cb + 8] = *(const uint4*)(bpl + 8);
        __syncthreads();
        half8 afh[4], afl[4], bfh[4], bfl[4];
        #pragma unroll
        for (int i = 0; i < 4; ++i) {
            afh[i] = *(const half8*)&AsH[(mb + i * 16 + r0) * 40 + quad * 8];
            if (ASPLIT == 1) afl[i] = *(const half8*)&AsL[(mb + i * 16 + r0) * 40 + quad * 8];
            bfh[i] = *(const half8*)&BsH[(nb + i * 16 + r0) * 40 + quad * 8];
            bfl[i] = *(const half8*)&BsL[(nb + i * 16 + r0) * 40 + quad * 8];
        }
        #pragma unroll
        for (int mi = 0; mi < 4; ++mi)
            #pragma unroll
            for (int ni = 0; ni < 4; ++ni) {
                acc[mi][ni] = __builtin_amdgcn_mfma_f32_16x16x32_f16(afh[mi], bfh[ni], acc[mi][ni], 0, 0, 0);
                if (ASPLIT == 1) acc[mi][ni] = __builtin_amdgcn_mfma_f32_16x16x32_f16(afl[mi], bfh[ni], acc[mi][ni], 0, 0, 0);
                acc[mi][ni] = __builtin_amdgcn_mfma_f32_16x16x32_f16(afh[mi], bfl[ni], acc[mi][ni], 0, 0, 0);
            }
        __syncthreads();
    }
    #pragma unroll
    for (int mi = 0; mi < 4; ++mi)
        #pragma unroll
        for (int ni = 0; ni < 4; ++ni)
            #pragma unroll
            for (int r = 0; r < 4; ++r) {
                int m = m0 + mb + mi * 16 + quad * 4 + r;
                int n = n0 + nb + ni * 16 + r0;
                float v = acc[mi][ni][r];
                if (EPI) {
                    v += bias[n] + res[(size_t)m * N + n];
                    ((float*)Cv)[(size_t)m * N + n] = v;
                } else {
                    ((fp16*)Cv)[(size_t)m * N + n] = (fp16)v;
                }
            }
}

// ---------------- exact logit parts ----------------
__global__ void tl_kernel(const float* __restrict__ attr, const float* __restrict__ u,
                          float* __restrict__ tl, int E_) {
    int p = blockIdx.x * blockDim.x + threadIdx.x;
    if (p >= E_) return;
    float a[16];
    #pragma unroll
    for (int k = 0; k < 16; ++k) a[k] = attr[(size_t)p * 16 + k];
    #pragma unroll
    for (int l = 0; l < 3; ++l)
        #pragma unroll
        for (int h = 0; h < 3; ++h) {
            float s = 0.f;
            #pragma unroll
            for (int k = 0; k < 16; ++k) s += a[k] * u[(l * 3 + h) * 16 + k];
            tl[(size_t)l * EE * 3 + p * 3 + h] = s;
        }
}
__global__ __launch_bounds__(256) void lilj_kernel(const float* __restrict__ outF,
    const float* __restrict__ va, const float* __restrict__ vj,
    float* __restrict__ li, float* __restrict__ lj, int Nn)
{
    int wid = blockIdx.x * 4 + (threadIdx.x >> 6);
    int lane = threadIdx.x & 63;
    int nw = gridDim.x * 4;
    float4 vah[3], vjh[3];
    #pragma unroll
    for (int h = 0; h < 3; ++h) {
        vah[h] = *(const float4*)&va[h * 256 + lane * 4];
        vjh[h] = *(const float4*)&vj[h * 256 + lane * 4];
    }
    for (int n = wid; n < Nn; n += nw) {
        float4 o = *(const float4*)&outF[(size_t)n * HH + lane * 4];
        #pragma unroll
        for (int h = 0; h < 3; ++h) {
            float sa = o.x * vah[h].x + o.y * vah[h].y + o.z * vah[h].z + o.w * vah[h].w;
            float sj = o.x * vjh[h].x + o.y * vjh[h].y + o.z * vjh[h].z + o.w * vjh[h].w;
            sa = wave_allreduce_sum(sa);
            sj = wave_allreduce_sum(sj);
            if (lane == 0) { li[n * 3 + h] = sa; lj[n * 3 + h] = sj; }
        }
    }
}

// ---------------- attention weights (exact logits -> normalized alpha) ----------------
__global__ __launch_bounds__(256) void alpha_kernel(const int* __restrict__ src_sorted,
    const int* __restrict__ offs, const float* __restrict__ tl,
    const float* __restrict__ li, const float* __restrict__ lj,
    float* __restrict__ alpha, int Nn)
{
    int idx = blockIdx.x * blockDim.x + threadIdx.x;
    if (idx >= Nn * 3) return;
    int node = idx / 3, h = idx % 3;
    int p0 = offs[node], p1 = offs[node + 1];
    if (p0 >= p1) return;
    float base = li[node * 3 + h];
    float m = -1e30f;
    for (int p = p0; p < p1; ++p) {
        float l = base + tl[p * 3 + h] + lj[src_sorted[p] * 3 + h];
        l = l >= 0.f ? l : 0.2f * l;
        m = fmaxf(m, l);
    }
    float s = 0.f;
    for (int p = p0; p < p1; ++p) {
        float l = base + tl[p * 3 + h] + lj[src_sorted[p] * 3 + h];
        l = l >= 0.f ? l : 0.2f * l;
        float w = expf(l - m);
        alpha[p * 3 + h] = w;
        s += w;
    }
    float inv = 1.f / (s + 1e-16f);
    for (int p = p0; p < p1; ++p) alpha[p * 3 + h] *= inv;
}

// ---------------- edge message kernel (r10-exact: serial loop, 68 VGPR, 7 waves/SIMD) ----------------
// r11 lesson: pairwise SWP raised VGPR 68->92, cut resident waves 7->5, regressed 155->196 us.
// Throughput here scales with resident waves; keep VGPR minimal.
__global__ __launch_bounds__(256) void edge_kernel(
    const fp16* __restrict__ xn, const float* __restrict__ attr,
    const int* __restrict__ src_sorted, const int* __restrict__ offs,
    const float* __restrict__ alpha, const float* __restrict__ We,
    fp16* __restrict__ aggr, int Nn)
{
    const int gw = blockIdx.x * 4 + (threadIdx.x >> 6);   // 3750 blocks -> 15000 waves
    const int lane = threadIdx.x & 63;
    const int h = gw % 3;
    const int slot = gw / 3;                              // 0..4999

    float WeR[4][16];
    #pragma unroll
    for (int j = 0; j < 4; ++j)
        #pragma unroll
        for (int k = 0; k < 16; ++k)
            WeR[j][k] = We[k * 768 + h * 256 + lane * 4 + j];

    for (int node = slot; node < Nn; node += 5000) {
        float acc[4] = {0.f, 0.f, 0.f, 0.f};
        int p0 = offs[node], p1 = offs[node + 1];
        for (int p = p0; p < p1; ++p) {
            int s = src_sorted[p];
            float a = alpha[p * 3 + h];
            half4 xr = *(const half4*)&xn[(size_t)s * HD3 + h * 256 + lane * 4];
            const float4* ap = (const float4*)&attr[(size_t)p * 16];
            float4 a0 = ap[0], a1 = ap[1], a2 = ap[2], a3 = ap[3];
            float av[16] = {a0.x, a0.y, a0.z, a0.w, a1.x, a1.y, a1.z, a1.w,
                            a2.x, a2.y, a2.z, a2.w, a3.x, a3.y, a3.z, a3.w};
            #pragma unroll
            for (int j = 0; j < 4; ++j) {
                float e = 0.f;
                #pragma unroll
                for (int k = 0; k < 16; ++k) e += av[k] * WeR[j][k];
                acc[j] += (a * (float)xr[j]) * e;
            }
        }
        half4 o;
        #pragma unroll
        for (int j = 0; j < 4; ++j) o[j] = (fp16)acc[j];
        *(half4*)&aggr[(size_t)node * HD3 + h * 256 + lane * 4] = o;
    }
}

// ---------------- Set2Set: fused LSTM cell + e + segment-softmax + r (block per graph) ----------------
// qh layout now [G, 512] = [h | r] (Whh folded into gates GEMM).
__global__ __launch_bounds__(256) void lstm_er_kernel(const float* __restrict__ gates,
    float* __restrict__ c, const int* __restrict__ go,
    const float* __restrict__ outf, float* __restrict__ qh)
{
    __shared__ float hh[256];
    __shared__ float esh[1024];
    __shared__ float red[256];
    int g = blockIdx.x, tid = threadIdx.x;
    const float* gr = gates + (size_t)g * 1024;
    float gi = gr[tid], gf = gr[256 + tid], gc = gr[512 + tid], gov = gr[768 + tid];
    float si = 1.f / (1.f + expf(-gi));
    float sf = 1.f / (1.f + expf(-gf));
    float so = 1.f / (1.f + expf(-gov));
    int cidx = g * HH + tid;
    float cn = sf * c[cidx] + si * tanhf(gc);
    float hn = so * tanhf(cn);
    c[cidx] = cn;
    qh[(size_t)g * 512 + tid] = hn;         // q_star[:, :H]
    hh[tid] = hn;
    int lane = tid & 63, wv = tid >> 6;
    int lo = go[g], hi = go[g + 1];
    float m = -1e30f, ssum = 0.f, racc = 0.f;
    __syncthreads();
    float4 hv = *(const float4*)&hh[lane * 4];
    for (int base = lo; base < hi; base += 1024) {
        int cnt = min(1024, hi - base);
        for (int i = wv; i < cnt; i += 4) {
            const float4 ov = *(const float4*)&outf[(size_t)(base + i) * HH + lane * 4];
            float pp = ov.x * hv.x + ov.y * hv.y + ov.z * hv.z + ov.w * hv.w;
            pp = wave_allreduce_sum(pp);
            if (lane == 0) esh[i] = pp;
        }
        __syncthreads();
        float lm = -1e30f;
        for (int i = tid; i < cnt; i += 256) lm = fmaxf(lm, esh[i]);
        red[tid] = lm; __syncthreads();
        for (int s = 128; s > 0; s >>= 1) { if (tid < s) red[tid] = fmaxf(red[tid], red[tid + s]); __syncthreads(); }
        float cm = red[0]; __syncthreads();
        float mn = fmaxf(m, cm);
        float scale = expf(m - mn);
        float ls = 0.f;
        for (int i = tid; i < cnt; i += 256) { float w = expf(esh[i] - mn); esh[i] = w; ls += w; }
        red[tid] = ls; __syncthreads();
        for (int s = 128; s > 0; s >>= 1) { if (tid < s) red[tid] += red[tid + s]; __syncthreads(); }
        float csum = red[0]; __syncthreads();
        ssum = ssum * scale + csum;
        racc *= scale;
        for (int i = 0; i < cnt; ++i)
            racc += esh[i] * outf[(size_t)(base + i) * HH + tid];
        m = mn;
        __syncthreads();
    }
    qh[(size_t)g * 512 + 256 + tid] = racc / (ssum + 1e-16f);
}

// ---------------- MLP head (fp32) ----------------
__global__ __launch_bounds__(256) void head_kernel(const float* __restrict__ qh,
    const float* __restrict__ W1, const float* __restrict__ b1,
    const float* __restrict__ lng, const float* __restrict__ lnb,
    const float* __restrict__ W2, const float* __restrict__ b2,
    float* __restrict__ outp)
{
    __shared__ float q[512];
    __shared__ float red[256];
    __shared__ float yl[256];
    int g = blockIdx.x, tid = threadIdx.x;
    q[tid] = qh[(size_t)g * 512 + tid];
    q[tid + 256] = qh[(size_t)g * 512 + 256 + tid];
    __syncthreads();
    float y = b1[tid];
    for (int k = 0; k < 512; ++k) y += q[k] * W1[k * 256 + tid];
    red[tid] = y; __syncthreads();
    for (int s = 128; s > 0; s >>= 1) { if (tid < s) red[tid] += red[tid + s]; __syncthreads(); }
    float mu = red[0] * (1.f / 256.f); __syncthreads();
    red[tid] = y * y; __syncthreads();
    for (int s = 128; s > 0; s >>= 1) { if (tid < s) red[tid] += red[tid + s]; __syncthreads(); }
    float var = red[0] * (1.f / 256.f) - mu * mu; __syncthreads();
    float yn = (y - mu) * rsqrtf(var + 1e-5f) * lng[tid] + lnb[tid];
    yl[tid] = fmaxf(yn, 0.f);
    __syncthreads();
    if (tid < 12) {
        float a = b2[tid];
        for (int d = 0; d < 256; ++d) a += yl[d] * W2[d * 12 + tid];
        outp[g * 12 + tid] = a;
    }
}

extern "C" void kernel_launch(void* const* d_in, const int* in_sizes, int n_in,
                              void* d_out, int out_size, void* d_ws, size_t ws_size,
                              hipStream_t stream)
{
    const float* x         = (const float*)d_in[0];
    const float* edge_attr = (const float*)d_in[1];
    const int*   edge_index= (const int*)d_in[2];
    const int*   batch     = (const int*)d_in[3];
    const float* proj_W    = (const float*)d_in[4];
    const float* proj_b    = (const float*)d_in[5];
    const float* Wn        = (const float*)d_in[6];
    const float* We        = (const float*)d_in[7];
    const float* Watt      = (const float*)d_in[8];
    const float* Ws        = (const float*)d_in[9];
    const float* bl        = (const float*)d_in[10];
    const float* W_ih      = (const float*)d_in[11];
    const float* W_hh      = (const float*)d_in[12];
    const float* b_ih      = (const float*)d_in[13];
    const float* b_hh      = (const float*)d_in[14];
    const float* mlp_W1    = (const float*)d_in[15];
    const float* mlp_b1    = (const float*)d_in[16];
    const float* ln_g      = (const float*)d_in[17];
    const float* ln_b      = (const float*)d_in[18];
    const float* mlp_W2    = (const float*)d_in[19];
    const float* mlp_b2    = (const float*)d_in[20];
    (void)in_sizes; (void)n_in; (void)out_size; (void)ws_size;

    char* p = (char*)d_ws;
    auto alloc = [&](size_t bytes) { char* r = p; p += (bytes + 255) & ~(size_t)255; return r; };

    // total ~198 MB (206 MB proven safe on this harness)
    int*   offs    = (int*)alloc((size_t)(NN + 1) * 4);
    int*   indeg   = (int*)alloc((size_t)NN * 4);
    int*   cursor  = (int*)alloc((size_t)NN * 4);
    int*   go      = (int*)alloc((size_t)(GG + 1) * 4);
    int*   bsum    = (int*)alloc((size_t)SCAN_NB * 4);
    int*   boff    = (int*)alloc((size_t)(SCAN_NB + 1) * 4);
    float* qh      = (float*)alloc((size_t)GG * 512 * 4);
    float* gates   = (float*)alloc((size_t)GG * 1024 * 4);
    float* cbuf    = (float*)alloc((size_t)GG * HH * 4);
    float* bsumv   = (float*)alloc((size_t)1024 * 4);
    float* ubuf    = (float*)alloc((size_t)144 * 4);
    float* vabuf   = (float*)alloc((size_t)2304 * 4);
    float* vjbuf   = (float*)alloc((size_t)2304 * 4);
    float* libuf   = (float*)alloc((size_t)NN * 3 * 4);
    float* ljbuf   = (float*)alloc((size_t)NN * 3 * 4);
    float* albuf   = (float*)alloc((size_t)EE * 3 * 4);
    fp16*  projWTh = (fp16*)alloc((size_t)HH * 64 * 2);
    fp16*  projWTl = (fp16*)alloc((size_t)HH * 64 * 2);
    fp16*  WnTh    = (fp16*)alloc((size_t)3 * HD3 * HH * 2);
    fp16*  WnTl    = (fp16*)alloc((size_t)3 * HD3 * HH * 2);
    fp16*  WsTh    = (fp16*)alloc((size_t)3 * HH * HD3 * 2);
    fp16*  WsTl    = (fp16*)alloc((size_t)3 * HH * HD3 * 2);
    fp16*  Wcombh  = (fp16*)alloc((size_t)1024 * 512 * 2);
    fp16*  Wcombl  = (fp16*)alloc((size_t)1024 * 512 * 2);
    int*   src_srt = (int*)alloc((size_t)EE * 4);
    float* attr_csr= (float*)alloc((size_t)EE * 16 * 4);
    float* tlbuf   = (float*)alloc((size_t)3 * EE * 3 * 4);
    float* outF32  = (float*)alloc((size_t)MP * HH * 4);
    fp16*  xn      = (fp16*)alloc((size_t)MP * HD3 * 2);
    fp16*  aggr    = (fp16*)alloc((size_t)MP * HD3 * 2);

    // one mega-prep launch: zeros, go, all weight transforms, u/va/vj
    prep_kernel<<<(PREP_TOTAL + 255) / 256, 256, 0, stream>>>(
        indeg, cursor, qh, cbuf, batch, go,
        proj_W, projWTh, projWTl, Wn, WnTh, WnTl, Ws, WsTh, WsTl,
        W_ih, W_hh, Wcombh, Wcombl, b_ih, b_hh, bsumv,
        We, Watt, ubuf, vabuf, vjbuf);

    hist_edge_kernel<<<(EE + 255) / 256, 256, 0, stream>>>(edge_index, indeg, EE);
    scan1_kernel<<<SCAN_NB, 256, 0, stream>>>(indeg, offs, bsum, NN);
    scan2_kernel<<<1, 256, 0, stream>>>(bsum, boff, SCAN_NB);
    scan3_kernel<<<SCAN_NB, 256, 0, stream>>>(offs, boff, NN, SCAN_NB);
    scatter_kernel<<<(EE + 255) / 256, 256, 0, stream>>>(edge_index, edge_attr, offs, cursor,
        src_srt, attr_csr, EE);
    tl_kernel<<<(EE + 255) / 256, 256, 0, stream>>>(attr_csr, ubuf, tlbuf, EE);

    // out = celu(x @ proj_W + proj_b): 64-tile split-3 MFMA, fp32 out
    gemm_s<1, 1, 0, 1, 1><<<dim3(NN / 64, HH / 64), 256, 0, stream>>>(
        x, projWTh, projWTl, outF32, proj_b, nullptr, NN, HH, 64);

    for (int l = 0; l < 3; ++l) {
        lilj_kernel<<<2500, 256, 0, stream>>>(outF32, vabuf + l * 768, vjbuf + l * 768,
            libuf, ljbuf, NN);
        alpha_kernel<<<(NN * 3 + 255) / 256, 256, 0, stream>>>(src_srt, offs,
            tlbuf + (size_t)l * EE * 3, libuf, ljbuf, albuf, NN);
        gemm128<1, 0><<<dim3(MP / 128, HD3 / 128), 256, 0, stream>>>(
            outF32, WnTh + (size_t)l * HD3 * HH, WnTl + (size_t)l * HD3 * HH,
            xn, nullptr, nullptr, MP, HD3, HH);
        edge_kernel<<<3750, 256, 0, stream>>>(xn, attr_csr, src_srt, offs,
            albuf, We + (size_t)l * 12288, aggr, NN);
        gemm128<0, 1><<<dim3(MP / 128, HH / 128), 256, 0, stream>>>(
            aggr, WsTh + (size_t)l * HH * HD3, WsTl + (size_t)l * HH * HD3,
            outF32, bl + (size_t)l * HH, outF32, MP, HH, HD3);
    }

    for (int s = 0; s < 6; ++s) {
        // gates = [h|r] @ Wcomb2^T + (b_ih + b_hh), K folded to 512
        gemm_s<1, 1, 0, 1, 0><<<dim3(GG / 64, 1024 / 64), 256, 0, stream>>>(
            qh, Wcombh, Wcombl, gates, bsumv, nullptr, GG, 1024, 512);
        lstm_er_kernel<<<GG, 256, 0, stream>>>(gates, cbuf, go, outF32, qh);
    }

    head_kernel<<<GG, 256, 0, stream>>>(qh, mlp_W1, mlp_b1, ln_g, ln_b, mlp_W2, mlp_b2, (float*)d_out);
}